// Round 4
// baseline (95.123 us; speedup 1.0000x reference)
//
#include <hip/hip_runtime.h>
#include <hip/hip_cooperative_groups.h>
#include <math.h>

namespace cg = cooperative_groups;

#define D 256
#define NUF 127.0f
#define C_MAX 128
#define TN 16384
#define T0F (-4.0f)
#define T1F (16.75f)
#define DTF ((T1F - T0F) / (float)(TN - 1))
#define INVDTF ((float)(TN - 1) / (T1F - T0F))
#define LN2F 0.69314718056f
#define RSU 44.3614195558365f  // ln(2^64)

// Miller downward recurrence (i = 254..1), linear space, 2^-64 rescale every
// P steps. Returns log(p_127/p_0) — identical truncation to the reference.
template<int P>
__device__ __forceinline__ float lratio1(float x) {
  float rx = 1.0f / fmaxf(x, 1e-10f);
  float a = 2.0f * rx;
  float cc = 508.0f * rx;
  float p = 1.0f, q = 0.0f, k = 0.0f;
  #pragma unroll
  for (int s = 0; s < 127; ++s) {  // i = 254..128; last step yields p_127
    float tn = fmaf(cc, p, q);
    cc -= a; q = p; p = tn;
    if ((s % P) == P - 1 || s == 126) {
      bool b = p > 0x1p64f;
      float sc = b ? 0x1p-64f : 1.0f;
      p *= sc; q *= sc; k += b ? 1.0f : 0.0f;
    }
  }
  float pn = p, kn = k;
  #pragma unroll
  for (int s = 0; s < 127; ++s) {  // i = 127..1
    float tn = fmaf(cc, p, q);
    cc -= a; q = p; p = tn;
    if ((s % P) == P - 1) {
      bool b = p > 0x1p64f;
      float sc = b ? 0x1p-64f : 1.0f;
      p *= sc; q *= sc; k += b ? 1.0f : 0.0f;
    }
  }
  return logf(pn) - logf(p) + (kn - k) * RSU;
}

// log(i0e(x)) via A&S 9.8.1/9.8.2 (|err| < 2e-7); t2 = log2(x)
__device__ __forceinline__ float li0e_f(float x, float t2) {
  if (x >= 3.75f) {
    float t = 3.75f / x;
    float P = 0.39894228f + t*(0.01328592f + t*(0.00225319f + t*(-0.00157565f +
              t*(0.00916281f + t*(-0.02057706f + t*(0.02635537f + t*(-0.01647633f +
              t*0.00392377f)))))));
    return logf(P) - 0.5f * LN2F * t2;
  } else {
    float u = x * (1.0f / 3.75f); u *= u;
    float P = 1.0f + u*(3.5156229f + u*(3.0899424f + u*(1.2067492f +
              u*(0.2659732f + u*(0.0360768f + u*0.0045813f)))));
    return logf(P) - x;
  }
}

// logit (without -logc) from s = x^2, table-interpolated Bessel ratio
__device__ __forceinline__ float logit_from(float s, const float* __restrict__ ltab) {
  float x = sqrtf(fmaxf(s, 1e-20f));
  float t2 = log2f(x);
  float fi = fminf(fmaxf((t2 - T0F) * INVDTF, 0.0f), (float)(TN - 1) - 0.001f);
  int i0 = (int)fi;
  float fr = fi - (float)i0;
  float l0 = ltab[i0], l1 = ltab[i0 + 1];
  float lr = fmaf(l1 - l0, fr, l0);
  return li0e_f(x, t2) + lr + x - NUF * (LN2F * t2);
}

__global__ __launch_bounds__(1024, 4) void k_all(
    const float* __restrict__ F, const float* __restrict__ Ave,
    const float* __restrict__ Amount, const int* __restrict__ labels,
    int N, int C, float* __restrict__ m2g, float* __restrict__ kap2,
    float* __restrict__ logc, float* __restrict__ ltab,
    float* __restrict__ partials, float* __restrict__ out) {
  __shared__ union __align__(16) SM {
    struct { int list[4096]; int wcnt[16]; float red[1024]; } prep;
    struct { float g[16][D]; float mt[8192]; float sf[16]; int lab[16];
             float redA[8][2][2]; float rowloss[16]; } dot;
  } sm;

  cg::grid_group grid = cg::this_grid();
  const int t = threadIdx.x;
  const int bid = blockIdx.x;
  const int lane = t & 63;

  // ---------------- PHASE 1 ----------------
  if (bid < C) {
    const int c = bid;
    const int w = t >> 6;
    int total = 0;
    for (int base = 0; base < N; base += 1024) {
      int row = base + t;
      bool m = (row < N) && (labels[row] == c);
      unsigned long long mask = __ballot(m);
      if (lane == 0) sm.prep.wcnt[w] = __popcll(mask);
      int before = __popcll(mask & ((1ULL << lane) - 1ULL));
      __syncthreads();
      int woff = total;
      #pragma unroll
      for (int i = 0; i < 16; ++i) { int v = sm.prep.wcnt[i]; if (i < w) woff += v; total += v; }
      if (m) sm.prep.list[woff + before] = row;
      __syncthreads();
    }
    const int d = t & 255, quarter = t >> 8;
    float acc = 0.0f;
    {
      int k = quarter;
      for (; k + 4 < total; k += 8) {
        int r0 = sm.prep.list[k], r1 = sm.prep.list[k + 4];
        float v0 = F[(size_t)r0 * D + d], v1 = F[(size_t)r1 * D + d];
        acc += v0; acc += v1;
      }
      for (; k < total; k += 4) acc += F[(size_t)sm.prep.list[k] * D + d];
    }
    sm.prep.red[t] = acc;
    __syncthreads();
    float anew = 0.0f;
    float fcnt = (float)total;
    if (t < 256) {
      float a = sm.prep.red[t] + sm.prep.red[t + 256] + sm.prep.red[t + 512] + sm.prep.red[t + 768];
      float ave = a / fmaxf(fcnt, 1.0f);
      float denom = fcnt + Amount[c];
      float wgt = (denom > 0.0f) ? (fcnt / denom) : 0.0f;
      anew = Ave[c * D + d] * (1.0f - wgt) + ave * wgt;
    }
    __syncthreads();
    sm.prep.red[t] = (t < 256) ? anew * anew : 0.0f;
    __syncthreads();
    for (int st = 128; st > 0; st >>= 1) {
      if (t < st) sm.prep.red[t] += sm.prep.red[t + st];
      __syncthreads();
    }
    float R2 = sm.prep.red[0];
    float R = sqrtf(R2);
    float kap = 256.0f * R / (1.0f - R2);
    if (kap > 100000.0f || kap < 0.0f) kap = 100000.0f;
    if (t < 256) {
      float mu = anew / fmaxf(R, 1e-12f);
      float m2v = 2.0f * kap * mu;
      int tile = d >> 6, plane = d & 1, d2 = (d >> 1) & 31;
      m2g[tile * 8192 + plane * 4096 + d2 * 128 + c] = m2v;
    }
    if (t == 0) {
      kap2[c] = kap * kap;
      float t2 = log2f(fmaxf(kap, 1e-10f));
      logc[c] = li0e_f(kap, t2) + lratio1<1>(kap) + kap - NUF * logf(kap + 1e-20f);
    }
  } else if (bid < C + 16) {
    int i = (bid - C) * 1024 + t;
    if (i < TN) {
      float x = exp2f(T0F + DTF * (float)i);
      ltab[i] = lratio1<4>(x);
    }
  } else if (bid == C + 16) {
    int npad = C_MAX - C;
    if (npad > 0) {
      for (int j = t; j < 256 * npad; j += 1024) {
        int cpad = C + (j % npad);
        int rest = j / npad;
        int d2 = rest & 31, plane = (rest >> 5) & 1, tile = rest >> 6;
        m2g[tile * 8192 + plane * 4096 + d2 * 128 + cpad] = 0.0f;
      }
      for (int j = t; j < npad; j += 1024) { kap2[C + j] = 0.0f; logc[C + j] = 0.0f; }
    }
  }

  grid.sync();

  // ---------------- PHASE 2: 16 rows per block ----------------
  const int c = t & 127, rq = t >> 7, half = (t >> 6) & 1;
  const int r0 = rq * 2, r1 = r0 + 1;
  float blockloss = 0.0f;

  for (int n0 = bid * 16; n0 < N; n0 += gridDim.x * 16) {
    { // stage 16 feature rows (x10), per-row ||g||^2, labels
      int srow = t >> 6;
      int sd = (t & 63) << 2;
      int n = n0 + srow;
      float4 v = make_float4(0.f, 0.f, 0.f, 0.f);
      if (n < N) v = *(const float4*)&F[(size_t)n * D + sd];
      v.x *= 10.f; v.y *= 10.f; v.z *= 10.f; v.w *= 10.f;
      *(float4*)&sm.dot.g[srow][sd] = v;
      float ps = v.x * v.x + v.y * v.y + v.z * v.z + v.w * v.w;
      #pragma unroll
      for (int off = 32; off > 0; off >>= 1) ps += __shfl_xor(ps, off, 64);
      if (lane == 0) sm.dot.sf[srow] = ps;
      if (t < 16) {
        sm.dot.lab[t] = (n0 + t < N) ? labels[n0 + t] : -1;
        sm.dot.rowloss[t] = 0.0f;
      }
    }

    float s0 = 0.f, s1 = 0.f;
    for (int tile = 0; tile < 4; ++tile) {
      __syncthreads();
      float4 mv0 = *(const float4*)&m2g[tile * 8192 + t * 8];
      float4 mv1 = *(const float4*)&m2g[tile * 8192 + t * 8 + 4];
      *(float4*)&sm.dot.mt[t * 8] = mv0;
      *(float4*)&sm.dot.mt[t * 8 + 4] = mv1;
      __syncthreads();
      const float* mA = sm.dot.mt;          // even dims
      const float* mB = sm.dot.mt + 4096;   // odd dims
      #pragma unroll
      for (int d2 = 0; d2 < 32; d2 += 2) {
        int dd = tile * 64 + d2 * 2;
        float a0 = mA[d2 * 128 + c];
        float b0 = mB[d2 * 128 + c];
        float a1 = mA[(d2 + 1) * 128 + c];
        float b1 = mB[(d2 + 1) * 128 + c];
        float4 gA = *(const float4*)&sm.dot.g[r0][dd];
        float4 gB = *(const float4*)&sm.dot.g[r1][dd];
        s0 = fmaf(a0, gA.x, s0); s0 = fmaf(b0, gA.y, s0);
        s0 = fmaf(a1, gA.z, s0); s0 = fmaf(b1, gA.w, s0);
        s1 = fmaf(a0, gB.x, s1); s1 = fmaf(b0, gB.y, s1);
        s1 = fmaf(a1, gB.z, s1); s1 = fmaf(b1, gB.w, s1);
      }
    }

    __syncthreads();
    float kk = kap2[c], lgc = logc[c];
    float lg0 = logit_from(s0 + kk + sm.dot.sf[r0], ltab) - lgc;
    float lg1 = logit_from(s1 + kk + sm.dot.sf[r1], ltab) - lgc;
    if (c >= C) { lg0 = -INFINITY; lg1 = -INFINITY; }

    float m0 = lg0, m1 = lg1;
    #pragma unroll
    for (int off = 32; off > 0; off >>= 1) {
      m0 = fmaxf(m0, __shfl_xor(m0, off, 64));
      m1 = fmaxf(m1, __shfl_xor(m1, off, 64));
    }
    if (lane == 0) { sm.dot.redA[rq][0][half] = m0; sm.dot.redA[rq][1][half] = m1; }
    __syncthreads();
    m0 = fmaxf(sm.dot.redA[rq][0][0], sm.dot.redA[rq][0][1]);
    m1 = fmaxf(sm.dot.redA[rq][1][0], sm.dot.redA[rq][1][1]);

    float e0 = expf(lg0 - m0);  // exp(-inf) = 0 covers padding
    float e1 = expf(lg1 - m1);
    #pragma unroll
    for (int off = 32; off > 0; off >>= 1) {
      e0 += __shfl_xor(e0, off, 64);
      e1 += __shfl_xor(e1, off, 64);
    }
    __syncthreads();
    if (lane == 0) { sm.dot.redA[rq][0][half] = e0; sm.dot.redA[rq][1][half] = e1; }
    __syncthreads();
    float lse0 = m0 + logf(sm.dot.redA[rq][0][0] + sm.dot.redA[rq][0][1]);
    float lse1 = m1 + logf(sm.dot.redA[rq][1][0] + sm.dot.redA[rq][1][1]);
    if (c == sm.dot.lab[r0] && n0 + r0 < N) sm.dot.rowloss[r0] = lse0 - lg0;
    if (c == sm.dot.lab[r1] && n0 + r1 < N) sm.dot.rowloss[r1] = lse1 - lg1;
    __syncthreads();
    if (t == 0) {
      float a = 0.f;
      #pragma unroll
      for (int j = 0; j < 16; ++j) a += sm.dot.rowloss[j];
      blockloss += a;
    }
    __syncthreads();  // protect LDS before next row-group restages
  }

  if (t == 0) partials[bid] = blockloss;

  grid.sync();

  // ---------------- PHASE 3: block 0 reduces ----------------
  if (bid == 0) {
    int nb = gridDim.x;
    float a = 0.f;
    if (t < nb) a = partials[t];
    sm.prep.red[t] = a;
    __syncthreads();
    for (int st = 512; st > 0; st >>= 1) {
      if (t < st) sm.prep.red[t] += sm.prep.red[t + st];
      __syncthreads();
    }
    if (t == 0) out[0] = sm.prep.red[0] / (float)N;
  }
}

extern "C" void kernel_launch(void* const* d_in, const int* in_sizes, int n_in,
                              void* d_out, int out_size, void* d_ws, size_t ws_size,
                              hipStream_t stream) {
  const float* F = (const float*)d_in[0];
  const float* Ave = (const float*)d_in[1];
  const float* Amount = (const float*)d_in[2];
  const int* labels = (const int*)d_in[3];
  int N = in_sizes[0] / D;
  int C = in_sizes[2];

  float* ws = (float*)d_ws;
  float* m2g = ws;               // 32768 floats
  float* kap2 = ws + 32768;      // 128
  float* logc = ws + 32896;      // 128
  float* ltab = ws + 33024;      // 16384
  float* partials = ws + 49408;  // 256
  float* out = (float*)d_out;

  void* args[] = {(void*)&F, (void*)&Ave, (void*)&Amount, (void*)&labels,
                  (void*)&N, (void*)&C, (void*)&m2g, (void*)&kap2,
                  (void*)&logc, (void*)&ltab, (void*)&partials, (void*)&out};
  hipLaunchCooperativeKernel((const void*)k_all, dim3(256), dim3(1024), args, 0, stream);
}

// Round 5
// 51.936 us; speedup vs baseline: 1.8315x; 1.8315x over previous
//
#include <hip/hip_runtime.h>
#include <math.h>

#define D 256
#define NUF 127.0f
#define C_MAX 128
#define TN 16384
#define T0F (-4.0f)
#define T1F (16.75f)
#define DTF ((T1F - T0F) / (float)(TN - 1))
#define INVDTF ((float)(TN - 1) / (T1F - T0F))
#define LN2F 0.69314718056f
#define RSU 44.3614195558365f  // ln(2^64)

// Miller downward recurrence (i = 254..1), linear space, 2^-64 rescale every
// P steps. Returns log(p_127/p_0) — identical truncation to the reference.
template<int P>
__device__ __forceinline__ float lratio1(float x) {
  float rx = 1.0f / fmaxf(x, 1e-10f);
  float a = 2.0f * rx;
  float cc = 508.0f * rx;  // 2i/x at i=254
  float p = 1.0f, q = 0.0f, k = 0.0f;
  #pragma unroll
  for (int s = 0; s < 127; ++s) {  // i = 254..128; last step yields p_127
    float tn = fmaf(cc, p, q);
    cc -= a; q = p; p = tn;
    if ((s % P) == P - 1 || s == 126) {
      bool b = p > 0x1p64f;
      float sc = b ? 0x1p-64f : 1.0f;
      p *= sc; q *= sc; k += b ? 1.0f : 0.0f;
    }
  }
  float pn = p, kn = k;
  #pragma unroll
  for (int s = 0; s < 127; ++s) {  // i = 127..1
    float tn = fmaf(cc, p, q);
    cc -= a; q = p; p = tn;
    if ((s % P) == P - 1) {
      bool b = p > 0x1p64f;
      float sc = b ? 0x1p-64f : 1.0f;
      p *= sc; q *= sc; k += b ? 1.0f : 0.0f;
    }
  }
  return logf(pn) - logf(p) + (kn - k) * RSU;
}

// log(i0e(x)) via A&S 9.8.1 / 9.8.2 (|err| < 2e-7); t2 = log2(x)
__device__ __forceinline__ float li0e_f(float x, float t2) {
  if (x >= 3.75f) {
    float t = 3.75f / x;
    float P = 0.39894228f + t*(0.01328592f + t*(0.00225319f + t*(-0.00157565f +
              t*(0.00916281f + t*(-0.02057706f + t*(0.02635537f + t*(-0.01647633f +
              t*0.00392377f)))))));
    return logf(P) - 0.5f * LN2F * t2;
  } else {
    float u = x * (1.0f / 3.75f); u *= u;
    float P = 1.0f + u*(3.5156229f + u*(3.0899424f + u*(1.2067492f +
              u*(0.2659732f + u*(0.0360768f + u*0.0045813f)))));
    return logf(P) - x;
  }
}

// logit (without -logc) from s = x^2, table-interpolated Bessel ratio
__device__ __forceinline__ float logit_from(float s, const float* __restrict__ ltab) {
  float x = sqrtf(fmaxf(s, 1e-20f));
  float t2 = log2f(x);
  float fi = fminf(fmaxf((t2 - T0F) * INVDTF, 0.0f), (float)(TN - 1) - 0.001f);
  int i0 = (int)fi;
  float fr = fi - (float)i0;
  float l0 = ltab[i0], l1 = ltab[i0 + 1];
  float lr = fmaf(l1 - l0, fr, l0);
  return li0e_f(x, t2) + lr + x - NUF * (LN2F * t2);
}

// blocks [0,C): per-class stats -> m2 (=2*kappa*mu, tiled planar), kap2, logc
// blocks [C, C+32): build the 16384-entry lr table; block C also zero-pads
// and zeroes the k_dot completion counter.
__global__ __launch_bounds__(512) void k_prep(
    const float* __restrict__ F, const float* __restrict__ Ave,
    const float* __restrict__ Amount, const int* __restrict__ labels,
    int N, int C, float* __restrict__ m2g, float* __restrict__ kap2,
    float* __restrict__ logc, float* __restrict__ ltab,
    unsigned* __restrict__ counter) {
  const int t = threadIdx.x;
  const int bid = blockIdx.x;
  if (bid >= C) {
    int i = (bid - C) * 512 + t;
    if (i < TN) {
      float x = exp2f(T0F + DTF * (float)i);
      ltab[i] = lratio1<4>(x);
    }
    if (bid == C) {
      if (t == 0)
        __hip_atomic_store(counter, 0u, __ATOMIC_RELAXED, __HIP_MEMORY_SCOPE_AGENT);
      if (C < C_MAX) {
        int npad = C_MAX - C;
        for (int j = t; j < 256 * npad; j += 512) {
          int cpad = C + (j % npad);
          int rest = j / npad;  // 0..255: tile(2b) plane(1b) d2(5b)
          int d2 = rest & 31, plane = (rest >> 5) & 1, tile = rest >> 6;
          m2g[tile * 8192 + plane * 4096 + d2 * 128 + cpad] = 0.0f;
        }
        for (int j = t; j < npad; j += 512) { kap2[C + j] = 0.0f; logc[C + j] = 0.0f; }
      }
    }
    return;
  }
  const int c = bid;
  const int lane = t & 63, w = t >> 6;
  __shared__ int list[4096];
  __shared__ int wcnt[8];
  __shared__ float red[512];

  // parallel ballot-compaction of matching row indices (deterministic order)
  int total = 0;
  for (int base = 0; base < N; base += 512) {
    int row = base + t;
    bool m = (row < N) && (labels[row] == c);
    unsigned long long mask = __ballot(m);
    if (lane == 0) wcnt[w] = __popcll(mask);
    int before = __popcll(mask & ((1ULL << lane) - 1ULL));
    __syncthreads();
    int woff = total;
    #pragma unroll
    for (int i = 0; i < 8; ++i) { int v = wcnt[i]; if (i < w) woff += v; total += v; }
    if (m) list[woff + before] = row;
    __syncthreads();
  }

  // two halves (512 threads) accumulate alternating list entries, coalesced
  const int d = t & 255, half = t >> 8;
  float acc = 0.0f;
  {
    int k = half;
    for (; k + 6 < total; k += 8) {
      int r0 = list[k], r1 = list[k + 2], r2 = list[k + 4], r3 = list[k + 6];
      float v0 = F[(size_t)r0 * D + d], v1 = F[(size_t)r1 * D + d];
      float v2 = F[(size_t)r2 * D + d], v3 = F[(size_t)r3 * D + d];
      acc += v0; acc += v1; acc += v2; acc += v3;
    }
    for (; k < total; k += 2) acc += F[(size_t)list[k] * D + d];
  }
  red[t] = acc;
  __syncthreads();
  float anew = 0.0f;
  float fcnt = (float)total;
  if (t < 256) {
    acc = red[t] + red[t + 256];
    float ave = acc / fmaxf(fcnt, 1.0f);
    float denom = fcnt + Amount[c];
    float wgt = (denom > 0.0f) ? (fcnt / denom) : 0.0f;
    anew = Ave[c * D + d] * (1.0f - wgt) + ave * wgt;
  }
  __syncthreads();
  red[t] = (t < 256) ? anew * anew : 0.0f;
  __syncthreads();
  for (int st = 256; st > 0; st >>= 1) {
    if (t < st) red[t] += red[t + st];
    __syncthreads();
  }
  float R2 = red[0];
  float R = sqrtf(R2);
  float kap = 256.0f * R / (1.0f - R2);
  if (kap > 100000.0f || kap < 0.0f) kap = 100000.0f;
  if (t < 256) {
    float mu = anew / fmaxf(R, 1e-12f);
    float m2v = 2.0f * kap * mu;
    int tile = d >> 6, plane = d & 1, d2 = (d >> 1) & 31;
    m2g[tile * 8192 + plane * 4096 + d2 * 128 + c] = m2v;
  }
  if (t == 0) {
    kap2[c] = kap * kap;
    float t2 = log2f(fmaxf(kap, 1e-10f));
    logc[c] = li0e_f(kap, t2) + lratio1<1>(kap) + kap - NUF * logf(kap + 1e-20f);
  }
}

// block = 8 rows x 128 classes (512 threads). s = kap2[c] + ||g||^2 + m2.g
// with m2 tiles staged in LDS; logits via table interp; fused row softmax;
// per-block partial loss; LAST block (agent-scope counter) does the final
// fixed-order reduction -> out. Deterministic: reduction order is by index.
__global__ __launch_bounds__(512) void k_dot(
    const float* __restrict__ F, const int* __restrict__ labels,
    const float* __restrict__ m2g, const float* __restrict__ kap2,
    const float* __restrict__ logc, const float* __restrict__ ltab,
    int N, int C, float* __restrict__ partials, unsigned* __restrict__ counter,
    float* __restrict__ out) {
  __shared__ float g[8][D];     // 8 KB, pre-scaled by 1/T = 10
  __shared__ float mt[8192];    // 32 KB: [plane][d2][c]; reused as reduce scratch
  __shared__ float sf[8];
  __shared__ int lab[8];
  __shared__ float redA[4][2][2];
  __shared__ float rowloss[8];
  __shared__ int lastflag;
  const int t = threadIdx.x;
  const int c = t & 127, rq = t >> 7, half = (t >> 6) & 1, lane = t & 63;
  const int n0 = blockIdx.x * 8;

  { // stage g + per-row ||g||^2 + labels (one wave per row)
    int srow = t >> 6;
    int sd = (t & 63) << 2;
    int n = n0 + srow;
    float4 v = make_float4(0.f, 0.f, 0.f, 0.f);
    if (n < N) v = *(const float4*)&F[(size_t)n * D + sd];
    v.x *= 10.f; v.y *= 10.f; v.z *= 10.f; v.w *= 10.f;
    *(float4*)&g[srow][sd] = v;
    float ps = v.x * v.x + v.y * v.y + v.z * v.z + v.w * v.w;
    #pragma unroll
    for (int off = 32; off > 0; off >>= 1) ps += __shfl_xor(ps, off, 64);
    if (lane == 0) sf[srow] = ps;
    if (t < 8) { lab[t] = (n0 + t < N) ? labels[n0 + t] : -1; rowloss[t] = 0.0f; }
  }

  float s0 = 0.f, s1 = 0.f;
  const int r0 = rq * 2, r1 = r0 + 1;
  for (int tile = 0; tile < 4; ++tile) {
    __syncthreads();
    #pragma unroll
    for (int p = 0; p < 4; ++p) {
      int idx = p * 2048 + t * 4;
      float4 mv = *(const float4*)&m2g[tile * 8192 + idx];
      *(float4*)&mt[idx] = mv;
    }
    __syncthreads();
    const float* mA = mt;         // d even
    const float* mB = mt + 4096;  // d odd
    #pragma unroll
    for (int d2 = 0; d2 < 32; d2 += 2) {
      int dd = tile * 64 + d2 * 2;
      float a0 = mA[d2 * 128 + c];
      float b0 = mB[d2 * 128 + c];
      float a1 = mA[(d2 + 1) * 128 + c];
      float b1 = mB[(d2 + 1) * 128 + c];
      float4 gA = *(const float4*)&g[r0][dd];
      float4 gB = *(const float4*)&g[r1][dd];
      s0 = fmaf(a0, gA.x, s0); s0 = fmaf(b0, gA.y, s0);
      s0 = fmaf(a1, gA.z, s0); s0 = fmaf(b1, gA.w, s0);
      s1 = fmaf(a0, gB.x, s1); s1 = fmaf(b0, gB.y, s1);
      s1 = fmaf(a1, gB.z, s1); s1 = fmaf(b1, gB.w, s1);
    }
  }

  __syncthreads();
  float kk = kap2[c], lgc = logc[c];
  float lg0 = logit_from(s0 + kk + sf[r0], ltab) - lgc;
  float lg1 = logit_from(s1 + kk + sf[r1], ltab) - lgc;
  if (c >= C) { lg0 = -INFINITY; lg1 = -INFINITY; }

  // row max across 128 class-threads (intra-wave shuffle + cross-wave LDS)
  float m0 = lg0, m1 = lg1;
  #pragma unroll
  for (int off = 32; off > 0; off >>= 1) {
    m0 = fmaxf(m0, __shfl_xor(m0, off, 64));
    m1 = fmaxf(m1, __shfl_xor(m1, off, 64));
  }
  if (lane == 0) { redA[rq][0][half] = m0; redA[rq][1][half] = m1; }
  __syncthreads();
  m0 = fmaxf(redA[rq][0][0], redA[rq][0][1]);
  m1 = fmaxf(redA[rq][1][0], redA[rq][1][1]);

  float e0 = expf(lg0 - m0);  // exp(-inf) = 0 handles padding
  float e1 = expf(lg1 - m1);
  #pragma unroll
  for (int off = 32; off > 0; off >>= 1) {
    e0 += __shfl_xor(e0, off, 64);
    e1 += __shfl_xor(e1, off, 64);
  }
  __syncthreads();  // all rq-groups done reading maxes before reuse
  if (lane == 0) { redA[rq][0][half] = e0; redA[rq][1][half] = e1; }
  __syncthreads();
  float sum0 = redA[rq][0][0] + redA[rq][0][1];
  float sum1 = redA[rq][1][0] + redA[rq][1][1];
  float lse0 = m0 + logf(sum0);
  float lse1 = m1 + logf(sum1);
  if (c == lab[r0]) rowloss[r0] = lse0 - lg0;
  if (c == lab[r1]) rowloss[r1] = lse1 - lg1;
  __syncthreads();

  if (t == 0) {
    float a = 0.f;
    #pragma unroll
    for (int j = 0; j < 8; ++j) a += rowloss[j];
    partials[blockIdx.x] = a;
    __threadfence();  // release: make partial visible device-wide
    unsigned old = __hip_atomic_fetch_add(counter, 1u, __ATOMIC_ACQ_REL,
                                          __HIP_MEMORY_SCOPE_AGENT);
    lastflag = (old == gridDim.x - 1) ? 1 : 0;
  }
  __syncthreads();

  if (lastflag) {  // last-arriving block: fixed-order final reduction
    __threadfence();  // acquire: see all other blocks' partials
    const int nb = (int)gridDim.x;
    float a = 0.f;
    for (int i = t; i < nb; i += 512) a += ((volatile float*)partials)[i];
    mt[t] = a;
    __syncthreads();
    for (int st = 256; st > 0; st >>= 1) {
      if (t < st) mt[t] += mt[t + st];
      __syncthreads();
    }
    if (t == 0) out[0] = mt[0] / (float)N;
  }
}

extern "C" void kernel_launch(void* const* d_in, const int* in_sizes, int n_in,
                              void* d_out, int out_size, void* d_ws, size_t ws_size,
                              hipStream_t stream) {
  const float* F = (const float*)d_in[0];
  const float* Ave = (const float*)d_in[1];
  const float* Amount = (const float*)d_in[2];
  const int* labels = (const int*)d_in[3];
  const int N = in_sizes[0] / D;
  const int C = in_sizes[2];

  float* ws = (float*)d_ws;
  float* m2g = ws;                       // 32768 floats
  float* kap2 = ws + 32768;              // 128
  float* logc = ws + 32896;              // 128
  float* ltab = ws + 33024;              // 16384
  float* partials = ws + 49408;          // up to 512
  unsigned* counter = (unsigned*)(ws + 49920);

  const int tb = (TN + 511) / 512;  // 32 table blocks
  k_prep<<<C + tb, 512, 0, stream>>>(F, Ave, Amount, labels, N, C, m2g, kap2,
                                     logc, ltab, counter);

  const int nb = (N + 7) / 8;
  k_dot<<<nb, 512, 0, stream>>>(F, labels, m2g, kap2, logc, ltab, N, C,
                                partials, counter, (float*)d_out);
}

// Round 6
// 27.134 us; speedup vs baseline: 3.5057x; 1.9141x over previous
//
#include <hip/hip_runtime.h>
#include <math.h>

#define D 256
#define NUF 127.0f
#define C_MAX 128
#define TN 16384
#define T0F (-4.0f)
#define T1F (16.75f)
#define DTF ((T1F - T0F) / (float)(TN - 1))
#define INVDTF ((float)(TN - 1) / (T1F - T0F))
#define LN2F 0.69314718056f
#define RSU 44.3614195558365f  // ln(2^64)

typedef __attribute__((ext_vector_type(8))) short bf16x8;
typedef __attribute__((ext_vector_type(4))) float f32x4;

// float -> bf16 bits, round-to-nearest-even
__device__ __forceinline__ unsigned short f2bf(float f) {
  unsigned u = __float_as_uint(f);
  u += 0x7FFFu + ((u >> 16) & 1u);
  return (unsigned short)(u >> 16);
}

// Miller downward recurrence (i = 254..1), linear space, 2^-64 rescale every
// P steps. Returns log(p_127/p_0) — identical truncation to the reference.
template<int P>
__device__ __forceinline__ float lratio1(float x) {
  float rx = 1.0f / fmaxf(x, 1e-10f);
  float a = 2.0f * rx;
  float cc = 508.0f * rx;  // 2i/x at i=254
  float p = 1.0f, q = 0.0f, k = 0.0f;
  #pragma unroll
  for (int s = 0; s < 127; ++s) {  // i = 254..128; last step yields p_127
    float tn = fmaf(cc, p, q);
    cc -= a; q = p; p = tn;
    if ((s % P) == P - 1 || s == 126) {
      bool b = p > 0x1p64f;
      float sc = b ? 0x1p-64f : 1.0f;
      p *= sc; q *= sc; k += b ? 1.0f : 0.0f;
    }
  }
  float pn = p, kn = k;
  #pragma unroll
  for (int s = 0; s < 127; ++s) {  // i = 127..1
    float tn = fmaf(cc, p, q);
    cc -= a; q = p; p = tn;
    if ((s % P) == P - 1) {
      bool b = p > 0x1p64f;
      float sc = b ? 0x1p-64f : 1.0f;
      p *= sc; q *= sc; k += b ? 1.0f : 0.0f;
    }
  }
  return logf(pn) - logf(p) + (kn - k) * RSU;
}

// log(i0e(x)) via A&S 9.8.1 / 9.8.2 (|err| < 2e-7); t2 = log2(x)
__device__ __forceinline__ float li0e_f(float x, float t2) {
  if (x >= 3.75f) {
    float t = 3.75f / x;
    float P = 0.39894228f + t*(0.01328592f + t*(0.00225319f + t*(-0.00157565f +
              t*(0.00916281f + t*(-0.02057706f + t*(0.02635537f + t*(-0.01647633f +
              t*0.00392377f)))))));
    return logf(P) - 0.5f * LN2F * t2;
  } else {
    float u = x * (1.0f / 3.75f); u *= u;
    float P = 1.0f + u*(3.5156229f + u*(3.0899424f + u*(1.2067492f +
              u*(0.2659732f + u*(0.0360768f + u*0.0045813f)))));
    return logf(P) - x;
  }
}

// logit (without -logc) from s = x^2, table-interpolated Bessel ratio
__device__ __forceinline__ float logit_from(float s, const float* __restrict__ ltab) {
  float x = sqrtf(fmaxf(s, 1e-20f));
  float t2 = log2f(x);
  float fi = fminf(fmaxf((t2 - T0F) * INVDTF, 0.0f), (float)(TN - 1) - 0.001f);
  int i0 = (int)fi;
  float fr = fi - (float)i0;
  float l0 = ltab[i0], l1 = ltab[i0 + 1];
  float lr = fmaf(l1 - l0, fr, l0);
  return li0e_f(x, t2) + lr + x - NUF * (LN2F * t2);
}

// blocks [0,C): per-class stats -> Bg (bf16(2*kappa*mu), [n][k] pre-swizzled),
//               kap2, logc. blocks [C, C+32): lr table; block C zero-pads.
__global__ __launch_bounds__(512) void k_prep(
    const float* __restrict__ F, const float* __restrict__ Ave,
    const float* __restrict__ Amount, const int* __restrict__ labels,
    int N, int C, unsigned short* __restrict__ Bg, float* __restrict__ kap2,
    float* __restrict__ logc, float* __restrict__ ltab) {
  const int t = threadIdx.x;
  const int bid = blockIdx.x;
  if (bid >= C) {
    int i = (bid - C) * 512 + t;
    if (i < TN) ltab[i] = lratio1<4>(exp2f(T0F + DTF * (float)i));
    if (bid == C && C < C_MAX) {
      uint4 z = make_uint4(0u, 0u, 0u, 0u);
      uint4* B4 = (uint4*)Bg;  // 32 uint4 per 512-byte class row
      for (int j = t; j < (C_MAX - C) * 32; j += 512) B4[C * 32 + j] = z;
      for (int j = t; j < C_MAX - C; j += 512) { kap2[C + j] = 0.0f; logc[C + j] = 0.0f; }
    }
    return;
  }
  const int c = bid;
  const int lane = t & 63, w = t >> 6;
  __shared__ int list[4096];
  __shared__ int wcnt[8];
  __shared__ float red[512];

  // parallel ballot-compaction of matching row indices (deterministic order)
  int total = 0;
  for (int base = 0; base < N; base += 512) {
    int row = base + t;
    bool m = (row < N) && (labels[row] == c);
    unsigned long long mask = __ballot(m);
    if (lane == 0) wcnt[w] = __popcll(mask);
    int before = __popcll(mask & ((1ULL << lane) - 1ULL));
    __syncthreads();
    int woff = total;
    #pragma unroll
    for (int i = 0; i < 8; ++i) { int v = wcnt[i]; if (i < w) woff += v; total += v; }
    if (m) list[woff + before] = row;
    __syncthreads();
  }

  // two halves accumulate alternating list entries, coalesced
  const int d = t & 255, half = t >> 8;
  float acc = 0.0f;
  {
    int k = half;
    for (; k + 6 < total; k += 8) {
      int r0 = list[k], r1 = list[k + 2], r2 = list[k + 4], r3 = list[k + 6];
      float v0 = F[(size_t)r0 * D + d], v1 = F[(size_t)r1 * D + d];
      float v2 = F[(size_t)r2 * D + d], v3 = F[(size_t)r3 * D + d];
      acc += v0; acc += v1; acc += v2; acc += v3;
    }
    for (; k < total; k += 2) acc += F[(size_t)list[k] * D + d];
  }
  red[t] = acc;
  __syncthreads();
  float anew = 0.0f;
  float fcnt = (float)total;
  if (t < 256) {
    acc = red[t] + red[t + 256];
    float ave = acc / fmaxf(fcnt, 1.0f);
    float denom = fcnt + Amount[c];
    float wgt = (denom > 0.0f) ? (fcnt / denom) : 0.0f;
    anew = Ave[c * D + d] * (1.0f - wgt) + ave * wgt;
  }
  __syncthreads();
  red[t] = (t < 256) ? anew * anew : 0.0f;
  __syncthreads();
  for (int st = 256; st > 0; st >>= 1) {
    if (t < st) red[t] += red[t + st];
    __syncthreads();
  }
  float R2 = red[0];
  float R = sqrtf(R2);
  float kap = 256.0f * R / (1.0f - R2);
  if (kap > 100000.0f || kap < 0.0f) kap = 100000.0f;
  if (t < 256) {
    float mu = anew / fmaxf(R, 1e-12f);
    unsigned short mb = f2bf(2.0f * kap * mu);
    // row c, k = d: 16B chunk index (d>>3) XOR-swizzled by (c&7)
    int ch = (d >> 3) ^ (c & 7);
    Bg[c * 256 + ch * 8 + (d & 7)] = mb;
  }
  if (t == 0) {
    kap2[c] = kap * kap;
    float t2 = log2f(fmaxf(kap, 1e-10f));
    logc[c] = li0e_f(kap, t2) + lratio1<1>(kap) + kap - NUF * logf(kap + 1e-20f);
  }
}

// block = 16 rows x 128 classes, 256 threads (4 waves).
// s = kap2[c] + ||10f||^2 + bf16GEMM(10f, 2*kappa*mu); logits via table;
// fused row softmax; per-block partial loss.
__global__ __launch_bounds__(256) void k_dot(
    const float* __restrict__ F, const int* __restrict__ labels,
    const unsigned short* __restrict__ Bg, const float* __restrict__ kap2,
    const float* __restrict__ logc, const float* __restrict__ ltab,
    int N, int C, float* __restrict__ partials) {
  __shared__ __align__(16) char Bs[65536];  // B tile [128 n][256 k] bf16, swizzled
  __shared__ __align__(16) char As[8192];   // A tile [16 m][256 k] bf16, swizzled
  __shared__ float sf[16];
  __shared__ float redm[4][16];
  __shared__ float reds[4][16];
  __shared__ float rowpart[16];
  __shared__ int labs[16];
  const int t = threadIdx.x;
  const int w = t >> 6, lane = t & 63;
  const int n0 = blockIdx.x * 16;

  // ---- B staging: 64 KB pre-swizzled bf16, global -> LDS async ----
  {
    const char* gsrc = (const char*)Bg + lane * 16;
    #pragma unroll
    for (int i = 0; i < 16; ++i) {
      int base = (w * 16 + i) * 1024;
      __builtin_amdgcn_global_load_lds(
          (const __attribute__((address_space(1))) void*)(gsrc + base),
          (__attribute__((address_space(3))) void*)&Bs[base], 16, 0, 0);
    }
  }

  // ---- A staging: 16 rows of 10*F -> swizzled bf16 LDS; sf; labels ----
  {
    const int arow = t >> 4, acol = t & 15;
    const int n = n0 + arow;
    float v[16];
    if (n < N) {
      const float4* fp = (const float4*)(F + (size_t)n * D + acol * 16);
      #pragma unroll
      for (int q = 0; q < 4; ++q) {
        float4 f4 = fp[q];
        v[q * 4 + 0] = f4.x * 10.f; v[q * 4 + 1] = f4.y * 10.f;
        v[q * 4 + 2] = f4.z * 10.f; v[q * 4 + 3] = f4.w * 10.f;
      }
    } else {
      #pragma unroll
      for (int e = 0; e < 16; ++e) v[e] = 0.0f;
    }
    float ps = 0.0f;
    #pragma unroll
    for (int e = 0; e < 16; ++e) ps = fmaf(v[e], v[e], ps);
    ps += __shfl_xor(ps, 1, 64); ps += __shfl_xor(ps, 2, 64);
    ps += __shfl_xor(ps, 4, 64); ps += __shfl_xor(ps, 8, 64);
    if (acol == 0) sf[arow] = ps;
    bf16x8 pk0, pk1;
    #pragma unroll
    for (int e = 0; e < 8; ++e) {
      pk0[e] = (short)f2bf(v[e]);
      pk1[e] = (short)f2bf(v[8 + e]);
    }
    int ch0 = (acol * 2) ^ (arow & 7);
    int ch1 = (acol * 2 + 1) ^ (arow & 7);
    *(bf16x8*)&As[arow * 512 + ch0 * 16] = pk0;
    *(bf16x8*)&As[arow * 512 + ch1 * 16] = pk1;
    if (t < 16) {
      labs[t] = (n0 + t < N) ? labels[n0 + t] : -1;
      rowpart[t] = 0.0f;
    }
  }
  asm volatile("s_waitcnt vmcnt(0)" ::: "memory");
  __syncthreads();

  // ---- GEMM: wave w owns n-tiles [w*32, w*32+16) and [w*32+16, w*32+32) ----
  f32x4 acc0 = {0.f, 0.f, 0.f, 0.f};
  f32x4 acc1 = {0.f, 0.f, 0.f, 0.f};
  const int lrow = lane & 15, lk = lane >> 4;
  const int nA = w * 32 + lrow, nB = nA + 16;
  #pragma unroll
  for (int s = 0; s < 8; ++s) {
    int kc = s * 4 + lk;
    bf16x8 a  = *(const bf16x8*)&As[lrow * 512 + ((kc ^ (lrow & 7)) << 4)];
    bf16x8 b0 = *(const bf16x8*)&Bs[nA * 512 + ((kc ^ (nA & 7)) << 4)];
    bf16x8 b1 = *(const bf16x8*)&Bs[nB * 512 + ((kc ^ (nB & 7)) << 4)];
    acc0 = __builtin_amdgcn_mfma_f32_16x16x32_bf16(a, b0, acc0, 0, 0, 0);
    acc1 = __builtin_amdgcn_mfma_f32_16x16x32_bf16(a, b1, acc1, 0, 0, 0);
  }

  // ---- logits: lane holds rows m = lk*4+r for classes nA, nB ----
  float kkA = kap2[nA], lgcA = logc[nA];
  float kkB = kap2[nB], lgcB = logc[nB];
  float lg0[4], lg1[4];
  #pragma unroll
  for (int r = 0; r < 4; ++r) {
    int m = lk * 4 + r;
    lg0[r] = logit_from(acc0[r] + kkA + sf[m], ltab) - lgcA;
    lg1[r] = logit_from(acc1[r] + kkB + sf[m], ltab) - lgcB;
  }
  if (nA >= C) {
    #pragma unroll
    for (int r = 0; r < 4; ++r) lg0[r] = -INFINITY;
  }
  if (nB >= C) {
    #pragma unroll
    for (int r = 0; r < 4; ++r) lg1[r] = -INFINITY;
  }

  // ---- row max: 16-lane shuffle (n within wave) + LDS (across waves) ----
  #pragma unroll
  for (int r = 0; r < 4; ++r) {
    float vmax = fmaxf(lg0[r], lg1[r]);
    vmax = fmaxf(vmax, __shfl_xor(vmax, 1, 64));
    vmax = fmaxf(vmax, __shfl_xor(vmax, 2, 64));
    vmax = fmaxf(vmax, __shfl_xor(vmax, 4, 64));
    vmax = fmaxf(vmax, __shfl_xor(vmax, 8, 64));
    if (lrow == 0) redm[w][lk * 4 + r] = vmax;
  }
  __syncthreads();
  float mrow[4];
  #pragma unroll
  for (int r = 0; r < 4; ++r) {
    int m = lk * 4 + r;
    mrow[r] = fmaxf(fmaxf(redm[0][m], redm[1][m]), fmaxf(redm[2][m], redm[3][m]));
    float e = expf(lg0[r] - mrow[r]) + expf(lg1[r] - mrow[r]);
    e += __shfl_xor(e, 1, 64); e += __shfl_xor(e, 2, 64);
    e += __shfl_xor(e, 4, 64); e += __shfl_xor(e, 8, 64);
    if (lrow == 0) reds[w][m] = e;
  }
  __syncthreads();
  #pragma unroll
  for (int r = 0; r < 4; ++r) {
    int m = lk * 4 + r;
    float lse = mrow[r] + logf(reds[0][m] + reds[1][m] + reds[2][m] + reds[3][m]);
    int lb = labs[m];
    if (nA == lb) rowpart[m] = lse - lg0[r];
    if (nB == lb) rowpart[m] = lse - lg1[r];
  }
  __syncthreads();
  if (t == 0) {
    float a = 0.f;
    #pragma unroll
    for (int j = 0; j < 16; ++j) a += rowpart[j];
    partials[blockIdx.x] = a;
  }
}

__global__ __launch_bounds__(256) void k_reduce(
    const float* __restrict__ partials, int nb, int N, float* __restrict__ out) {
  __shared__ float red[256];
  float s = 0.0f;
  for (int i = threadIdx.x; i < nb; i += 256) s += partials[i];
  red[threadIdx.x] = s;
  __syncthreads();
  for (int st = 128; st > 0; st >>= 1) {
    if (threadIdx.x < st) red[threadIdx.x] += red[threadIdx.x + st];
    __syncthreads();
  }
  if (threadIdx.x == 0) out[0] = red[0] / (float)N;
}

extern "C" void kernel_launch(void* const* d_in, const int* in_sizes, int n_in,
                              void* d_out, int out_size, void* d_ws, size_t ws_size,
                              hipStream_t stream) {
  const float* F = (const float*)d_in[0];
  const float* Ave = (const float*)d_in[1];
  const float* Amount = (const float*)d_in[2];
  const int* labels = (const int*)d_in[3];
  const int N = in_sizes[0] / D;
  const int C = in_sizes[2];

  unsigned short* Bg = (unsigned short*)d_ws;        // 65536 B: [128 n][256 k] bf16 swz
  float* kap2 = (float*)((char*)d_ws + 65536);       // 128
  float* logc = kap2 + C_MAX;                        // 128
  float* ltab = logc + C_MAX;                        // 16384
  float* partials = ltab + TN;                       // nb

  k_prep<<<C + 32, 512, 0, stream>>>(F, Ave, Amount, labels, N, C, Bg, kap2,
                                     logc, ltab);
  const int nb = (N + 15) / 16;
  k_dot<<<nb, 256, 0, stream>>>(F, labels, Bg, kap2, logc, ltab, N, C, partials);
  k_reduce<<<1, 256, 0, stream>>>(partials, nb, N, (float*)d_out);
}